// Round 4
// baseline (220.462 us; speedup 1.0000x reference)
//
#include <hip/hip_runtime.h>

typedef __attribute__((ext_vector_type(4))) float f32x4;
typedef __attribute__((ext_vector_type(8))) short s16x8;

__device__ __forceinline__ ushort f2bf(float f) {
  unsigned u = __float_as_uint(f);
  return (ushort)((u + 0x7fffu + ((u >> 16) & 1u)) >> 16);
}

// ---------------- f32 -> bf16 conversion ----------------
__global__ __launch_bounds__(256) void cvt_bf16(const float4* __restrict__ in,
                                                ushort* __restrict__ out, int n4) {
  int stride = gridDim.x * blockDim.x;
  for (int i = blockIdx.x * blockDim.x + threadIdx.x; i < n4; i += stride) {
    float4 v = in[i];
    uint2 o;
    o.x = (unsigned)f2bf(v.x) | ((unsigned)f2bf(v.y) << 16);
    o.y = (unsigned)f2bf(v.z) | ((unsigned)f2bf(v.w) << 16);
    *(uint2*)(out + (size_t)i * 4) = o;
  }
}

__global__ __launch_bounds__(256) void cvt_bf16_w4(const float4* __restrict__ a,
                                                   const float4* __restrict__ b,
                                                   const float4* __restrict__ c,
                                                   const float4* __restrict__ d,
                                                   ushort* __restrict__ oa, ushort* __restrict__ ob,
                                                   ushort* __restrict__ oc, ushort* __restrict__ od) {
  int idx = blockIdx.x * 256 + threadIdx.x;  // 4096 blocks = 4*262144
  int sel = idx >> 18, k = idx & 262143;
  const float4* src = sel == 0 ? a : sel == 1 ? b : sel == 2 ? c : d;
  ushort* dst = sel == 0 ? oa : sel == 1 ? ob : sel == 2 ? oc : od;
  float4 v = src[k];
  uint2 o;
  o.x = (unsigned)f2bf(v.x) | ((unsigned)f2bf(v.y) << 16);
  o.y = (unsigned)f2bf(v.z) | ((unsigned)f2bf(v.w) << 16);
  *(uint2*)(dst + (size_t)k * 4) = o;
}

__device__ __forceinline__ void gload_lds16(const void* g, void* l) {
  __builtin_amdgcn_global_load_lds((const __attribute__((address_space(1))) void*)g,
                                   (__attribute__((address_space(3))) void*)l, 16, 0, 0);
}

// swizzled LDS read: linear [row][128B] with byte-col XOR ((row&7)<<4)
__device__ __forceinline__ const s16x8* ldsrd(const char* base, int row, int cb) {
  return (const s16x8*)(base + row * 128 + (cb ^ ((row & 7) << 4)));
}

// ============ fused K+V projection: 256x256 tile, 8-wave, 8-phase ============
// Counted-vmcnt schedule (T4): phases consume A-quarters in order (row remap
// i*32+wm*16), B consumed at loop top -> regions die phase-by-phase, so tile
// t+2 stages into the CURRENT buffer's dead regions. One vmcnt(7)/K-tile.
__global__ __launch_bounds__(512, 1) void gemm256_kv(
    const ushort* __restrict__ A, const ushort* __restrict__ Bw,
    const float* __restrict__ biasK, const float* __restrict__ biasV,
    ushort* __restrict__ Ko, ushort* __restrict__ Vt, float* __restrict__ Tsum,
    int M, int K) {
  __shared__ char lds[131072];  // A dbuf 2x32KB @0, B dbuf 2x32KB @64KB
  const int tid = threadIdx.x;
  const int lane = tid & 63, wid = tid >> 6;
  const int g = lane >> 4, r = lane & 15;
  const int wm = wid >> 2, wn = wid & 3;
  const int bid = blockIdx.x;
  const int n0 = (bid & 7) * 256;   // XCD-aligned: each XCD owns one B panel
  const int m0 = (bid >> 3) * 256;

  const size_t rowB = (size_t)2 * K;
  // staging: quarter q = 64 rows x 128B = 8KB = one gload_lds16 per thread.
  // LDS dest linear (tid*16); global source chunk pre-XORed by (row&7) (rule 21).
  const char* Ag0 = (const char*)A + (size_t)(m0 + (tid >> 3)) * rowB +
                    ((size_t)((tid & 7) ^ ((tid >> 3) & 7)) << 4);
  const char* Bg0 = (const char*)Bw + (size_t)(n0 + (tid >> 3)) * rowB +
                    ((size_t)((tid & 7) ^ ((tid >> 3) & 7)) << 4);

  f32x4 acc[8][4] = {};

  auto sA = [&](int t, int q) {
    gload_lds16(Ag0 + (size_t)q * 64 * rowB + (size_t)t * 128,
                lds + (t & 1) * 32768 + q * 8192 + tid * 16);
  };
  auto sB = [&](int t, int q) {
    gload_lds16(Bg0 + (size_t)q * 64 * rowB + (size_t)t * 128,
                lds + 65536 + (t & 1) * 32768 + q * 8192 + tid * 16);
  };

  const int NT = K >> 6;

  // prologue: tile0 full (8), tile1 first 7 (A-q3 deferred to iter0 ph0)
  sA(0, 0); sA(0, 1); sA(0, 2); sA(0, 3);
  sB(0, 0); sB(0, 1); sB(0, 2); sB(0, 3);
  sA(1, 0); sB(1, 0); sB(1, 1);
  sA(1, 1); sB(1, 2); sB(1, 3);
  sA(1, 2);
  asm volatile("s_waitcnt vmcnt(7)" ::: "memory");
  __builtin_amdgcn_s_barrier();

#define GPHASE(I0, EXTRA)                                                                  \
  {                                                                                        \
    s16x8 aq[2][2];                                                                        \
    _Pragma("unroll") for (int ii = 0; ii < 2; ++ii)                                       \
        _Pragma("unroll") for (int kk = 0; kk < 2; ++kk)                                   \
            aq[ii][kk] = *ldsrd(Ab, (I0 + ii) * 32 + wm * 16 + r, kk * 64 + g * 16);       \
    EXTRA;                                                                                 \
    __builtin_amdgcn_s_barrier();                                                          \
    asm volatile("s_waitcnt lgkmcnt(0)" ::: "memory");                                     \
    __builtin_amdgcn_sched_barrier(0);                                                     \
    __builtin_amdgcn_s_setprio(1);                                                         \
    _Pragma("unroll") for (int ii = 0; ii < 2; ++ii)                                       \
        _Pragma("unroll") for (int ni = 0; ni < 4; ++ni)                                   \
            _Pragma("unroll") for (int kk = 0; kk < 2; ++kk)                               \
                acc[I0 + ii][ni] = __builtin_amdgcn_mfma_f32_16x16x32_bf16(                \
                    aq[ii][kk], bf[ni][kk], acc[I0 + ii][ni], 0, 0, 0);                    \
    __builtin_amdgcn_s_setprio(0);                                                         \
  }

  for (int t = 0; t < NT; ++t) {
    const char* Ab = lds + (t & 1) * 32768;
    const char* Bb = lds + 65536 + (t & 1) * 32768;
    const bool m1 = (t + 1 < NT), m2 = (t + 2 < NT);
    s16x8 bf[4][2];
#pragma unroll
    for (int ni = 0; ni < 4; ++ni)
#pragma unroll
      for (int kk = 0; kk < 2; ++kk)
        bf[ni][kk] = *ldsrd(Bb, wn * 64 + ni * 16 + r, kk * 64 + g * 16);

    GPHASE(0, if (m1) sA(t + 1, 3));
    __builtin_amdgcn_s_barrier();
    GPHASE(2, if (m2) { sA(t + 2, 0); sB(t + 2, 0); sB(t + 2, 1); });
    __builtin_amdgcn_s_barrier();
    GPHASE(4, if (m2) { sA(t + 2, 1); sB(t + 2, 2); sB(t + 2, 3); });
    __builtin_amdgcn_s_barrier();
    GPHASE(6, if (m2) sA(t + 2, 2));
    if (t < NT - 2)
      asm volatile("s_waitcnt vmcnt(7)" ::: "memory");
    else
      asm volatile("s_waitcnt vmcnt(0)" ::: "memory");
    __builtin_amdgcn_s_barrier();
  }
#undef GPHASE

  // epilogue; acc row i -> global row m0 + i*32 + wm*16 + g*4
  if (n0 < 1024) {
#pragma unroll
    for (int ni = 0; ni < 4; ++ni) {
      const int n = n0 + wn * 64 + ni * 16 + r;
      const float bv = biasK[n];
#pragma unroll
      for (int i = 0; i < 8; ++i) {
        const int mb = m0 + i * 32 + wm * 16 + g * 4;
#pragma unroll
        for (int j = 0; j < 4; ++j)
          Ko[(size_t)(mb + j) * 1024 + n] = f2bf(acc[i][ni][j] + bv);
      }
    }
  } else {
    float* Lts = (float*)lds;  // [4 q][256 n] cross-wave partials
#pragma unroll
    for (int ni = 0; ni < 4; ++ni) {
      const int nv = n0 - 1024 + wn * 64 + ni * 16 + r;
      const float bv = biasV[nv];
#pragma unroll
      for (int i = 0; i < 8; ++i) {
        const int mb = m0 + i * 32 + wm * 16 + g * 4;
        const int bbi = mb >> 11, tt = mb & 2047;
        uint2 val;
        val.x = (unsigned)f2bf(acc[i][ni][0] + bv) | ((unsigned)f2bf(acc[i][ni][1] + bv) << 16);
        val.y = (unsigned)f2bf(acc[i][ni][2] + bv) | ((unsigned)f2bf(acc[i][ni][3] + bv) << 16);
        *(uint2*)(Vt + ((size_t)bbi * 1024 + nv) * 2048 + tt) = val;
      }
    }
    // per-64-row-tile column sums: wave wm covers 32 of each tile's 64 rows
    float part[4][4];
#pragma unroll
    for (int ni = 0; ni < 4; ++ni)
#pragma unroll
      for (int q = 0; q < 4; ++q) {
        float s = 0.0f;
#pragma unroll
        for (int ii = 0; ii < 2; ++ii)
#pragma unroll
          for (int j = 0; j < 4; ++j) s += acc[2 * q + ii][ni][j];
        s += __shfl_xor(s, 16);
        s += __shfl_xor(s, 32);
        part[ni][q] = s;
      }
    __syncthreads();  // loop's final barrier already passed; safe to reuse lds
    if (wm == 0 && g == 0) {
#pragma unroll
      for (int ni = 0; ni < 4; ++ni)
#pragma unroll
        for (int q = 0; q < 4; ++q) Lts[q * 256 + wn * 64 + ni * 16 + r] = part[ni][q];
    }
    __syncthreads();
    if (wm == 1 && g == 0) {
#pragma unroll
      for (int ni = 0; ni < 4; ++ni) {
        const int nv = n0 - 1024 + wn * 64 + ni * 16 + r;
        const float bv = biasV[nv];
#pragma unroll
        for (int q = 0; q < 4; ++q) {
          const int gt = (m0 + q * 64) >> 6;
          const int bbi = gt >> 5, tl = gt & 31;
          Tsum[((size_t)(bbi * 16 + (nv >> 6)) * 33 + tl) * 64 + (nv & 63)] =
              part[ni][q] + Lts[q * 256 + wn * 64 + ni * 16 + r] + 64.0f * bv;
        }
      }
    }
  }
}

// ---------------- 128x128 GEMM (Q and O projections) ----------------
template <int EPI>
__global__ __launch_bounds__(256) void gemm_bt(const ushort* __restrict__ A,
                                               const ushort* __restrict__ B,
                                               const float* __restrict__ bias,
                                               void* __restrict__ Cout, float oscale,
                                               int M, int N, int K) {
  __shared__ ushort As[128 * 32];
  __shared__ ushort Bs[128 * 32];
  const int tid = threadIdx.x;
  const int lane = tid & 63, w = tid >> 6;
  const int g = lane >> 4, r = lane & 15;
  const int m0 = blockIdx.x * 128, n0 = blockIdx.y * 128;
  const int wm = (w >> 1) * 64, wn = (w & 1) * 64;

  const int srow = tid >> 2;
  const int scb = (tid & 3) * 16;
  const char* Ag = (const char*)(A + (size_t)(m0 + srow) * K) + scb;
  const char* Bg = (const char*)(B + (size_t)(n0 + srow) * K) + scb;
  char* AsB = (char*)As + (tid & 192) * 16;
  char* BsB = (char*)Bs + (tid & 192) * 16;
  const size_t rowskip = (size_t)64 * K * sizeof(ushort);

  f32x4 acc[4][4] = {};

  for (int k0 = 0; k0 < K; k0 += 32) {
    gload_lds16(Ag + (size_t)k0 * 2, AsB);
    gload_lds16(Ag + rowskip + (size_t)k0 * 2, AsB + 4096);
    gload_lds16(Bg + (size_t)k0 * 2, BsB);
    gload_lds16(Bg + rowskip + (size_t)k0 * 2, BsB + 4096);
    __syncthreads();
    s16x8 af[4], bf[4];
#pragma unroll
    for (int i = 0; i < 4; ++i) af[i] = *(const s16x8*)&As[(wm + i * 16 + r) * 32 + g * 8];
#pragma unroll
    for (int i = 0; i < 4; ++i) bf[i] = *(const s16x8*)&Bs[(wn + i * 16 + r) * 32 + g * 8];
#pragma unroll
    for (int mi = 0; mi < 4; ++mi)
#pragma unroll
      for (int ni = 0; ni < 4; ++ni)
        acc[mi][ni] =
            __builtin_amdgcn_mfma_f32_16x16x32_bf16(af[mi], bf[ni], acc[mi][ni], 0, 0, 0);
    __syncthreads();
  }

  if constexpr (EPI == 0) {
    ushort* C = (ushort*)Cout;
#pragma unroll
    for (int ni = 0; ni < 4; ++ni) {
      const int n = n0 + wn + ni * 16 + r;
      const float bv = bias[n];
#pragma unroll
      for (int mi = 0; mi < 4; ++mi) {
        const int mb = m0 + wm + mi * 16 + g * 4;
#pragma unroll
        for (int j = 0; j < 4; ++j)
          C[(size_t)(mb + j) * N + n] = f2bf((acc[mi][ni][j] + bv) * oscale);
      }
    }
  } else {
    float* C = (float*)Cout;
#pragma unroll
    for (int ni = 0; ni < 4; ++ni) {
      const int n = n0 + wn + ni * 16 + r;
      const float bv = bias[n];
#pragma unroll
      for (int mi = 0; mi < 4; ++mi) {
        const int mb = m0 + wm + mi * 16 + g * 4;
#pragma unroll
        for (int j = 0; j < 4; ++j)
          C[(size_t)(mb + j) * N + n] = acc[mi][ni][j] + bv;
      }
    }
  }
}

// suffix-sum over tiles: Vsuf[b][h][t][d] = sum_{t'>=t} tilesum  (t=0..32, [32]=0)
__global__ __launch_bounds__(64) void vsuffix(float* __restrict__ T) {
  const int bh = blockIdx.x;
  const int d = threadIdx.x;
  float* p = T + (size_t)bh * 33 * 64 + d;
  float run = 0.0f;
  p[32 * 64] = 0.0f;
  for (int t = 31; t >= 0; --t) {
    run += p[t * 64];
    p[t * 64] = run;
  }
}

// ---------------- fused masked attention ----------------
__device__ __forceinline__ ushort* swz(ushort* base, int row, int colb) {
  return (ushort*)((char*)base + row * 128 + (colb ^ ((row & 7) << 4)));
}

__global__ __launch_bounds__(256) void attn_fwd(
    const ushort* __restrict__ Q, const ushort* __restrict__ Km,
    const ushort* __restrict__ Vt, const float* __restrict__ Vsuf,
    const int* __restrict__ dlen, const int* __restrict__ elen,
    ushort* __restrict__ Oatt) {
  const int tid = threadIdx.x;
  const int lane = tid & 63, w = tid >> 6;
  const int g = lane >> 4, r = lane & 15;
  const int qt = blockIdx.x, b = blockIdx.y, h = blockIdx.z;
  const int dl = dlen[b], el = elen[b];
  const float* VS = Vsuf + (size_t)(b * 16 + h) * 33 * 64;

  if (qt * 64 >= dl) {
    const int qrow = qt * 64 + w * 16 + g * 4;
#pragma unroll
    for (int dt = 0; dt < 4; ++dt) {
      const ushort hv = f2bf(VS[dt * 16 + r] * (1.0f / 2048.0f));
#pragma unroll
      for (int j = 0; j < 4; ++j)
        Oatt[(size_t)(b * 512 + qrow + j) * 1024 + h * 64 + dt * 16 + r] = hv;
    }
    return;
  }

  __shared__ ushort Ks[64 * 64];
  __shared__ ushort Vs[64 * 64];
  __shared__ ushort Ps[4 * 16 * 64];
  ushort* PsW = Ps + w * 16 * 64;
  const int qbase = qt * 64 + w * 16;

  s16x8 qf[2];
  {
    const ushort* qp = Q + (size_t)(b * 512 + qbase + r) * 1024 + h * 64 + g * 8;
    qf[0] = *(const s16x8*)qp;
    qf[1] = *(const s16x8*)(qp + 32);
  }

  f32x4 o[4] = {};
  float lrow[4] = {0.0f, 0.0f, 0.0f, 0.0f};
  bool qok[4];
#pragma unroll
  for (int j = 0; j < 4; ++j) qok[j] = (qbase + g * 4 + j) < dl;

  const int sr = tid >> 3;
  const int sc8 = (tid & 7) * 8;
  const int scb = sc8 * 2;
  const ushort* Kg = Km + (size_t)(b * 2048 + sr) * 1024 + h * 64 + sc8;
  const ushort* Vg = Vt + ((size_t)b * 1024 + h * 64 + sr) * 2048 + sc8;

  const int t_last = (el - 1) >> 6;

  s16x8 pk0, pk1, pv0, pv1;
  {
    pk0 = *(const s16x8*)(Kg);
    pk1 = *(const s16x8*)(Kg + (size_t)32 * 1024);
    pv0 = *(const s16x8*)(Vg);
    pv1 = *(const s16x8*)(Vg + (size_t)32 * 2048);
  }

  for (int t = 0; t <= t_last; ++t) {
    *(s16x8*)swz(Ks, sr, scb) = pk0;
    *(s16x8*)swz(Ks, sr + 32, scb) = pk1;
    *(s16x8*)swz(Vs, sr, scb) = pv0;
    *(s16x8*)swz(Vs, sr + 32, scb) = pv1;
    __syncthreads();

    if (t < t_last) {
      const int kv0 = (t + 1) * 64;
      pk0 = *(const s16x8*)(Kg + (size_t)kv0 * 1024);
      pk1 = *(const s16x8*)(Kg + (size_t)(kv0 + 32) * 1024);
      pv0 = *(const s16x8*)(Vg + kv0);
      pv1 = *(const s16x8*)(Vg + (size_t)32 * 2048 + kv0);
    }

    const int kv0 = t * 64;
    float p[4][4];
#pragma unroll
    for (int nt = 0; nt < 4; ++nt) {
      f32x4 s = {};
      s16x8 kf0 = *(const s16x8*)swz(Ks, nt * 16 + r, g * 16);
      s16x8 kf1 = *(const s16x8*)swz(Ks, nt * 16 + r, 64 + g * 16);
      s = __builtin_amdgcn_mfma_f32_16x16x32_bf16(qf[0], kf0, s, 0, 0, 0);
      s = __builtin_amdgcn_mfma_f32_16x16x32_bf16(qf[1], kf1, s, 0, 0, 0);
      const bool kok = (kv0 + nt * 16 + r) < el;
#pragma unroll
      for (int j = 0; j < 4; ++j) {
        const float pe = __builtin_amdgcn_exp2f(s[j]);
        p[nt][j] = (kok && qok[j]) ? pe : 1.0f;
      }
    }
#pragma unroll
    for (int nt = 0; nt < 4; ++nt)
#pragma unroll
      for (int j = 0; j < 4; ++j) lrow[j] += p[nt][j];

#pragma unroll
    for (int nt = 0; nt < 4; ++nt) {
#pragma unroll
      for (int jp = 0; jp < 4; jp += 2) {
        unsigned pk;
        asm("v_cvt_pk_bf16_f32 %0, %1, %2" : "=v"(pk) : "v"(p[nt][jp]), "v"(p[nt][jp + 1]));
        *swz(PsW, g * 4 + jp, (nt * 16 + r) * 2) = (ushort)pk;
        *swz(PsW, g * 4 + jp + 1, (nt * 16 + r) * 2) = (ushort)(pk >> 16);
      }
    }

#pragma unroll
    for (int kc = 0; kc < 2; ++kc) {
      s16x8 pf = *(const s16x8*)swz(PsW, r, kc * 64 + g * 16);
#pragma unroll
      for (int dt = 0; dt < 4; ++dt) {
        s16x8 vf = *(const s16x8*)swz(Vs, dt * 16 + r, kc * 64 + g * 16);
        o[dt] = __builtin_amdgcn_mfma_f32_16x16x32_bf16(pf, vf, o[dt], 0, 0, 0);
      }
    }
    __syncthreads();
  }

  const float tailcnt = (float)(2048 - (t_last + 1) * 64);
  const float* VT = VS + (t_last + 1) * 64;
#pragma unroll
  for (int dt = 0; dt < 4; ++dt) {
    const float tv = VT[dt * 16 + r];
#pragma unroll
    for (int j = 0; j < 4; ++j) o[dt][j] += tv;
  }

  float inv[4];
#pragma unroll
  for (int j = 0; j < 4; ++j) {
    float s = lrow[j];
    s += __shfl_xor(s, 1);
    s += __shfl_xor(s, 2);
    s += __shfl_xor(s, 4);
    s += __shfl_xor(s, 8);
    inv[j] = 1.0f / (s + tailcnt);
  }
#pragma unroll
  for (int dt = 0; dt < 4; ++dt)
#pragma unroll
    for (int j = 0; j < 4; ++j)
      Oatt[(size_t)(b * 512 + qbase + g * 4 + j) * 1024 + h * 64 + dt * 16 + r] =
          f2bf(o[dt][j] * inv[j]);
}

// ---------------- launch ----------------
extern "C" void kernel_launch(void* const* d_in, const int* in_sizes, int n_in,
                              void* d_out, int out_size, void* d_ws, size_t ws_size,
                              hipStream_t stream) {
  const float* enc  = (const float*)d_in[0];
  const float* fq   = (const float*)d_in[1];
  const int* dlen   = (const int*)d_in[2];
  const int* elen   = (const int*)d_in[3];
  const float* wq_w = (const float*)d_in[4];
  const float* wq_b = (const float*)d_in[5];
  const float* wk_w = (const float*)d_in[6];
  const float* wk_b = (const float*)d_in[7];
  const float* wv_w = (const float*)d_in[8];
  const float* wv_b = (const float*)d_in[9];
  const float* wo_w = (const float*)d_in[10];
  const float* wo_b = (const float*)d_in[11];

  char* ws = (char*)d_ws;
  ushort* enc16 = (ushort*)(ws + 0);           // 32 MB
  ushort* fq16  = (ushort*)(ws + 33554432);    // 8 MB (reused as Vsuf after Q-proj)
  float*  Vsuf  = (float*)(ws + 33554432);     // ~1 MB alias of fq16 (safe: sequential)
  ushort* wq16  = (ushort*)(ws + 41943040);    // 2 MB
  ushort* wk16  = (ushort*)(ws + 44040192);    // 2 MB  | adjacent: [wk;wv] = B concat
  ushort* wv16  = (ushort*)(ws + 46137344);    // 2 MB  |
  ushort* wo16  = (ushort*)(ws + 48234496);    // 2 MB
  ushort* Qw    = (ushort*)(ws + 50331648);    // 8 MB
  ushort* Kw    = (ushort*)(ws + 58720256);    // 32 MB
  ushort* Vtw   = (ushort*)(ws + 92274688);    // 32 MB  [B][1024][2048]
  ushort* attw  = (ushort*)(ws + 125829120);   // 8 MB

  cvt_bf16<<<2048, 256, 0, stream>>>((const float4*)enc, enc16, 16384 * 1024 / 4);
  cvt_bf16<<<1024, 256, 0, stream>>>((const float4*)fq, fq16, 4096 * 1024 / 4);
  cvt_bf16_w4<<<4096, 256, 0, stream>>>((const float4*)wq_w, (const float4*)wk_w,
                                        (const float4*)wv_w, (const float4*)wo_w,
                                        wq16, wk16, wv16, wo16);

  const float qscale = 0.125f * 1.44269504088896340736f;
  gemm_bt<0><<<dim3(32, 8), 256, 0, stream>>>(fq16, wq16, wq_b, Qw, qscale, 4096, 1024, 1024);

  gemm256_kv<<<512, 512, 0, stream>>>(enc16, wk16, wk_b, wv_b, Kw, Vtw, Vsuf, 16384, 1024);
  vsuffix<<<128, 64, 0, stream>>>(Vsuf);

  attn_fwd<<<dim3(8, 8, 16), 256, 0, stream>>>(Qw, Kw, Vtw, Vsuf, dlen, elen, attw);

  gemm_bt<2><<<dim3(32, 8), 256, 0, stream>>>(attw, wo16, wo_b, d_out, 1.0f, 4096, 1024, 1024);
}